// Round 5
// baseline (190.742 us; speedup 1.0000x reference)
//
#include <hip/hip_runtime.h>

// Problem constants (B,C,D,H,W) = (2,4,96,160,160)
#define NB 2
#define NC 4
#define ND 96
#define NH 160
#define NW 160

// Math (verified exact rounds 1-4): sy == sz (identical 2D 3x3 kernels),
// depth padding adds only zero slices, sobel(p)-sobel(t) = sobel(q) with
// q = softmax(pred) - onehot(target):
//   loss = sum(gx^2 + 2*gy^2) * SCALE
// separable: d = q[x+1]-q[x-1], s = q[x-1]+2q[x]+q[x+1],
//            gx = d[y-1]+2d[y]+d[y+1], gy = s[y+1]-s[y-1].
//
// Structure: full-width bands of TH=8 output rows. Staging is float4/int4
// vectorized, fixed-trip, fully unrolled, ALL in named registers (round 4's
// local arrays spilled to scratch: 128 MB of WRITE_SIZE). LDS = 25.6 KB.
constexpr int TH    = 8;              // output rows per band
constexpr int SR    = TH + 2;         // staged rows (vertical halo)
constexpr int NBAND = NH / TH;        // 20 bands per slice
constexpr int PITCH = NW;             // staged row pitch in float4 cells
constexpr int NCELL = SR * PITCH;     // 1600 cells (float4 each) = 25.6 KB
constexpr int NSLOT = NCELL / 4;      // 400 4-pixel staging slots
constexpr float SCALE = 1.0f / (2.0f * 98.0f * 162.0f * 162.0f * 4.0f);

// Rotate 16-B cells within each 64-B group so a thread's 4 consecutive
// ds_write_b128 spread banks; reads are a lane-permutation of consecutive
// cells (conflict-free). Measured cost r4: 0.77M cyc (~0.3 us) - acceptable.
__device__ __forceinline__ int cell(int i) {
    return (i & ~3) | ((i + (i >> 2)) & 3);
}

// One pixel: softmax over 4 class logits minus onehot(target).
__device__ __forceinline__ float4 qcalc(float p0, float p1, float p2, float p3,
                                        int t, bool valid) {
    float4 v = make_float4(0.f, 0.f, 0.f, 0.f);
    if (valid) {
        const float m  = fmaxf(fmaxf(p0, p1), fmaxf(p2, p3));
        const float e0 = __expf(p0 - m);
        const float e1 = __expf(p1 - m);
        const float e2 = __expf(p2 - m);
        const float e3 = __expf(p3 - m);
        const float inv = 1.0f / (e0 + e1 + e2 + e3);
        v.x = e0 * inv - (t == 0 ? 1.f : 0.f);
        v.y = e1 * inv - (t == 1 ? 1.f : 0.f);
        v.z = e2 * inv - (t == 2 ? 1.f : 0.f);
        v.w = e3 * inv - (t == 3 ? 1.f : 0.f);
    }
    return v;
}

__global__ __launch_bounds__(256, 6) void boundary_loss_kernel(
    const float* __restrict__ pred,   // (B,C,D,H,W) f32
    const int*   __restrict__ target, // (B,D,H,W) i32
    float* __restrict__ out)          // scalar, pre-zeroed
{
    __shared__ float4 q4s[NCELL];     // 25.6 KB, swizzled class-interleaved
    __shared__ float wsum[4];

    const int tid   = threadIdx.x;
    const int slice = blockIdx.y;     // b*ND + d
    const int b     = slice / ND;
    const int d     = slice - b * ND;
    const int y0    = blockIdx.x * TH;

    const size_t cs4   = (size_t)ND * NH * NW / 4;   // class stride in float4
    const size_t pbase = ((size_t)b * NC * ND + d) * (size_t)(NH * NW);
    const size_t tbase = ((size_t)b * ND + d) * (size_t)(NH * NW);

    // ---- Load phase: slot A = tid, slot B = tid + 256 (tid < 144) ----
    const int  rA   = tid / 40;
    const int  cA   = tid - rA * 40;
    const int  gyA  = y0 - 1 + rA;
    const bool vA   = (gyA >= 0) && (gyA < NH);
    const int  gyAc = min(max(gyA, 0), NH - 1);

    const int  sB   = tid + 256;
    const bool hasB = (sB < NSLOT);
    const int  rB   = sB / 40;
    const int  cB   = sB - rB * 40;
    const int  gyB  = y0 - 1 + rB;
    const bool vB   = hasB && (gyB >= 0) && (gyB < NH);
    const int  gyBc = min(max(gyB, 0), NH - 1);

    // All loads into NAMED registers (no local arrays -> no scratch spill).
    const float4* ppA = (const float4*)(pred + pbase + (size_t)gyAc * NW) + cA;
    const float4 a0 = ppA[0];
    const float4 a1 = ppA[cs4];
    const float4 a2 = ppA[2 * cs4];
    const float4 a3 = ppA[3 * cs4];
    const int4   ta = ((const int4*)(target + tbase + (size_t)gyAc * NW))[cA];

    const int cBs = hasB ? cB : 0;   // safe address for inactive threads
    const int gyBs = hasB ? gyBc : 0;
    const float4* ppB = (const float4*)(pred + pbase + (size_t)gyBs * NW) + cBs;
    const float4 b0 = ppB[0];
    const float4 b1 = ppB[cs4];
    const float4 b2 = ppB[2 * cs4];
    const float4 b3 = ppB[3 * cs4];
    const int4   tb = ((const int4*)(target + tbase + (size_t)gyBs * NW))[cBs];

    // ---- Softmax + stage into LDS (explicit components, no arrays) ----
    {
        const int fA = rA * PITCH + 4 * cA;
        q4s[cell(fA + 0)] = qcalc(a0.x, a1.x, a2.x, a3.x, ta.x, vA);
        q4s[cell(fA + 1)] = qcalc(a0.y, a1.y, a2.y, a3.y, ta.y, vA);
        q4s[cell(fA + 2)] = qcalc(a0.z, a1.z, a2.z, a3.z, ta.z, vA);
        q4s[cell(fA + 3)] = qcalc(a0.w, a1.w, a2.w, a3.w, ta.w, vA);
    }
    if (hasB) {
        const int fB = rB * PITCH + 4 * cB;
        q4s[cell(fB + 0)] = qcalc(b0.x, b1.x, b2.x, b3.x, tb.x, vB);
        q4s[cell(fB + 1)] = qcalc(b0.y, b1.y, b2.y, b3.y, tb.y, vB);
        q4s[cell(fB + 2)] = qcalc(b0.z, b1.z, b2.z, b3.z, tb.z, vB);
        q4s[cell(fB + 3)] = qcalc(b0.w, b1.w, b2.w, b3.w, tb.w, vB);
    }
    __syncthreads();

    // ---- Vertical rolling Sobel: thread t owns column x = t (t < 160) ----
    float acc = 0.f;
    if (tid < NW) {
        float smm0 = 0.f, sm0 = 0.f, dmm0 = 0.f, dm0 = 0.f;
        float smm1 = 0.f, sm1 = 0.f, dmm1 = 0.f, dm1 = 0.f;
        float smm2 = 0.f, sm2 = 0.f, dmm2 = 0.f, dm2 = 0.f;
        float smm3 = 0.f, sm3 = 0.f, dmm3 = 0.f, dm3 = 0.f;

#define CLS(L, M, R, smm, sm, dmm, dm)                                    \
        do {                                                              \
            const float sn = (L) + 2.f * (M) + (R);                       \
            const float dn = (R) - (L);                                   \
            if (t >= 2) {                                                 \
                const float gx = (dmm) + 2.f * (dm) + dn;                 \
                const float gy = sn - (smm);                              \
                acc += gx * gx + 2.f * gy * gy;                           \
            }                                                             \
            smm = sm; sm = sn; dmm = dm; dm = dn;                         \
        } while (0)

        #pragma unroll
        for (int t = 0; t < SR; ++t) {
            const int base = t * PITCH + tid;
            const float4 qm = q4s[cell(base)];
            float4 ql = make_float4(0.f, 0.f, 0.f, 0.f);
            float4 qr = make_float4(0.f, 0.f, 0.f, 0.f);
            if (tid > 0)      ql = q4s[cell(base - 1)];
            if (tid < NW - 1) qr = q4s[cell(base + 1)];
            CLS(ql.x, qm.x, qr.x, smm0, sm0, dmm0, dm0);
            CLS(ql.y, qm.y, qr.y, smm1, sm1, dmm1, dm1);
            CLS(ql.z, qm.z, qr.z, smm2, sm2, dmm2, dm2);
            CLS(ql.w, qm.w, qr.w, smm3, sm3, dmm3, dm3);
        }
#undef CLS
    }

    // ---- Block reduction -> one atomic per block ----
    #pragma unroll
    for (int off = 32; off > 0; off >>= 1)
        acc += __shfl_down(acc, off, 64);
    if ((tid & 63) == 0) wsum[tid >> 6] = acc;
    __syncthreads();
    if (tid == 0) {
        const float s = wsum[0] + wsum[1] + wsum[2] + wsum[3];
        atomicAdd(out, s * SCALE);
    }
}

extern "C" void kernel_launch(void* const* d_in, const int* in_sizes, int n_in,
                              void* d_out, int out_size, void* d_ws, size_t ws_size,
                              hipStream_t stream) {
    const float* pred   = (const float*)d_in[0];
    const int*   target = (const int*)d_in[1];
    float*       out    = (float*)d_out;

    // d_out is poisoned with 0xAA before every launch — zero the scalar first.
    hipMemsetAsync(out, 0, sizeof(float), stream);

    dim3 grid(NBAND, NB * ND);   // 20 x 192 = 3840 blocks
    boundary_loss_kernel<<<grid, 256, 0, stream>>>(pred, target, out);
}

// Round 6
// 157.749 us; speedup vs baseline: 1.2092x; 1.2092x over previous
//
#include <hip/hip_runtime.h>

// Problem constants (B,C,D,H,W) = (2,4,96,160,160)
#define NB 2
#define NC 4
#define ND 96
#define NH 160
#define NW 160

// Math (verified exact rounds 1-5): sy == sz (identical 2D 3x3 kernels),
// depth padding adds only zero slices, sobel(p)-sobel(t) = sobel(q) with
// q = softmax(pred) - onehot(target):
//   loss = sum(gx^2 + 2*gy^2) * SCALE
// separable: d = q[x+1]-q[x-1], s = q[x-1]+2q[x]+q[x+1],
//            gx = d[y-1]+2d[y]+d[y+1], gy = s[y+1]-s[y-1].
//
// Structure: full-width bands of TH=8 output rows, float4/int4 staging,
// rolling vertical Sobel. NOTE: __launch_bounds__ has NO min-waves arg —
// (256,6) capped VGPRs at ~84 and the allocator spilled the 8 in-flight
// float4 loads to scratch: 128 B/thread = the 128 MB WRITE_SIZE seen in
// rounds 4-5. Do not re-add an occupancy floor here.
constexpr int TH    = 8;              // output rows per band
constexpr int SR    = TH + 2;         // staged rows (vertical halo)
constexpr int NBAND = NH / TH;        // 20 bands per slice
constexpr int PITCH = NW;             // staged row pitch in float4 cells
constexpr int NCELL = SR * PITCH;     // 1600 cells (float4 each) = 25.6 KB
constexpr int NSLOT = NCELL / 4;      // 400 4-pixel staging slots
constexpr float SCALE = 1.0f / (2.0f * 98.0f * 162.0f * 162.0f * 4.0f);

// Rotate 16-B cells within each 64-B group so a thread's 4 consecutive
// ds_write_b128 spread banks; reads are a lane-permutation of consecutive
// cells (conflict-free). Measured cost: 0.77M cyc (~0.3 us) - acceptable.
__device__ __forceinline__ int cell(int i) {
    return (i & ~3) | ((i + (i >> 2)) & 3);
}

// One pixel: softmax over 4 class logits minus onehot(target).
__device__ __forceinline__ float4 qcalc(float p0, float p1, float p2, float p3,
                                        int t, bool valid) {
    float4 v = make_float4(0.f, 0.f, 0.f, 0.f);
    if (valid) {
        const float m  = fmaxf(fmaxf(p0, p1), fmaxf(p2, p3));
        const float e0 = __expf(p0 - m);
        const float e1 = __expf(p1 - m);
        const float e2 = __expf(p2 - m);
        const float e3 = __expf(p3 - m);
        const float inv = 1.0f / (e0 + e1 + e2 + e3);
        v.x = e0 * inv - (t == 0 ? 1.f : 0.f);
        v.y = e1 * inv - (t == 1 ? 1.f : 0.f);
        v.z = e2 * inv - (t == 2 ? 1.f : 0.f);
        v.w = e3 * inv - (t == 3 ? 1.f : 0.f);
    }
    return v;
}

__global__ __launch_bounds__(256) void boundary_loss_kernel(
    const float* __restrict__ pred,   // (B,C,D,H,W) f32
    const int*   __restrict__ target, // (B,D,H,W) i32
    float* __restrict__ out)          // scalar, pre-zeroed
{
    __shared__ float4 q4s[NCELL];     // 25.6 KB, swizzled class-interleaved
    __shared__ float wsum[4];

    const int tid   = threadIdx.x;
    const int slice = blockIdx.y;     // b*ND + d
    const int b     = slice / ND;
    const int d     = slice - b * ND;
    const int y0    = blockIdx.x * TH;

    const size_t cs4   = (size_t)ND * NH * NW / 4;   // class stride in float4
    const size_t pbase = ((size_t)b * NC * ND + d) * (size_t)(NH * NW);
    const size_t tbase = ((size_t)b * ND + d) * (size_t)(NH * NW);

    // ---- Load phase: slot A = tid, slot B = tid + 256 (tid < 144) ----
    const int  rA   = tid / 40;
    const int  cA   = tid - rA * 40;
    const int  gyA  = y0 - 1 + rA;
    const bool vA   = (gyA >= 0) && (gyA < NH);
    const int  gyAc = min(max(gyA, 0), NH - 1);

    const int  sB   = tid + 256;
    const bool hasB = (sB < NSLOT);
    const int  rB   = sB / 40;
    const int  cB   = sB - rB * 40;
    const int  gyB  = y0 - 1 + rB;
    const bool vB   = hasB && (gyB >= 0) && (gyB < NH);
    const int  gyBc = min(max(gyB, 0), NH - 1);

    // All loads into named registers, issued back-to-back (one latency
    // exposure); default VGPR budget keeps them resident (no scratch).
    const float4* ppA = (const float4*)(pred + pbase + (size_t)gyAc * NW) + cA;
    const float4 a0 = ppA[0];
    const float4 a1 = ppA[cs4];
    const float4 a2 = ppA[2 * cs4];
    const float4 a3 = ppA[3 * cs4];
    const int4   ta = ((const int4*)(target + tbase + (size_t)gyAc * NW))[cA];

    const int cBs  = hasB ? cB : 0;   // safe address for inactive threads
    const int gyBs = hasB ? gyBc : 0;
    const float4* ppB = (const float4*)(pred + pbase + (size_t)gyBs * NW) + cBs;
    const float4 b0 = ppB[0];
    const float4 b1 = ppB[cs4];
    const float4 b2 = ppB[2 * cs4];
    const float4 b3 = ppB[3 * cs4];
    const int4   tb = ((const int4*)(target + tbase + (size_t)gyBs * NW))[cBs];

    // ---- Softmax + stage into LDS (explicit components, no arrays) ----
    {
        const int fA = rA * PITCH + 4 * cA;
        q4s[cell(fA + 0)] = qcalc(a0.x, a1.x, a2.x, a3.x, ta.x, vA);
        q4s[cell(fA + 1)] = qcalc(a0.y, a1.y, a2.y, a3.y, ta.y, vA);
        q4s[cell(fA + 2)] = qcalc(a0.z, a1.z, a2.z, a3.z, ta.z, vA);
        q4s[cell(fA + 3)] = qcalc(a0.w, a1.w, a2.w, a3.w, ta.w, vA);
    }
    if (hasB) {
        const int fB = rB * PITCH + 4 * cB;
        q4s[cell(fB + 0)] = qcalc(b0.x, b1.x, b2.x, b3.x, tb.x, vB);
        q4s[cell(fB + 1)] = qcalc(b0.y, b1.y, b2.y, b3.y, tb.y, vB);
        q4s[cell(fB + 2)] = qcalc(b0.z, b1.z, b2.z, b3.z, tb.z, vB);
        q4s[cell(fB + 3)] = qcalc(b0.w, b1.w, b2.w, b3.w, tb.w, vB);
    }
    __syncthreads();

    // ---- Vertical rolling Sobel: thread t owns column x = t (t < 160) ----
    float acc = 0.f;
    if (tid < NW) {
        float smm0 = 0.f, sm0 = 0.f, dmm0 = 0.f, dm0 = 0.f;
        float smm1 = 0.f, sm1 = 0.f, dmm1 = 0.f, dm1 = 0.f;
        float smm2 = 0.f, sm2 = 0.f, dmm2 = 0.f, dm2 = 0.f;
        float smm3 = 0.f, sm3 = 0.f, dmm3 = 0.f, dm3 = 0.f;

#define CLS(L, M, R, smm, sm, dmm, dm)                                    \
        do {                                                              \
            const float sn = (L) + 2.f * (M) + (R);                       \
            const float dn = (R) - (L);                                   \
            if (t >= 2) {                                                 \
                const float gx = (dmm) + 2.f * (dm) + dn;                 \
                const float gy = sn - (smm);                              \
                acc += gx * gx + 2.f * gy * gy;                           \
            }                                                             \
            smm = sm; sm = sn; dmm = dm; dm = dn;                         \
        } while (0)

        #pragma unroll
        for (int t = 0; t < SR; ++t) {
            const int base = t * PITCH + tid;
            const float4 qm = q4s[cell(base)];
            float4 ql = make_float4(0.f, 0.f, 0.f, 0.f);
            float4 qr = make_float4(0.f, 0.f, 0.f, 0.f);
            if (tid > 0)      ql = q4s[cell(base - 1)];
            if (tid < NW - 1) qr = q4s[cell(base + 1)];
            CLS(ql.x, qm.x, qr.x, smm0, sm0, dmm0, dm0);
            CLS(ql.y, qm.y, qr.y, smm1, sm1, dmm1, dm1);
            CLS(ql.z, qm.z, qr.z, smm2, sm2, dmm2, dm2);
            CLS(ql.w, qm.w, qr.w, smm3, sm3, dmm3, dm3);
        }
#undef CLS
    }

    // ---- Block reduction -> one atomic per block ----
    #pragma unroll
    for (int off = 32; off > 0; off >>= 1)
        acc += __shfl_down(acc, off, 64);
    if ((tid & 63) == 0) wsum[tid >> 6] = acc;
    __syncthreads();
    if (tid == 0) {
        const float s = wsum[0] + wsum[1] + wsum[2] + wsum[3];
        atomicAdd(out, s * SCALE);
    }
}

extern "C" void kernel_launch(void* const* d_in, const int* in_sizes, int n_in,
                              void* d_out, int out_size, void* d_ws, size_t ws_size,
                              hipStream_t stream) {
    const float* pred   = (const float*)d_in[0];
    const int*   target = (const int*)d_in[1];
    float*       out    = (float*)d_out;

    // d_out is poisoned with 0xAA before every launch — zero the scalar first.
    hipMemsetAsync(out, 0, sizeof(float), stream);

    dim3 grid(NBAND, NB * ND);   // 20 x 192 = 3840 blocks
    boundary_loss_kernel<<<grid, 256, 0, stream>>>(pred, target, out);
}

// Round 7
// 131.858 us; speedup vs baseline: 1.4466x; 1.1964x over previous
//
#include <hip/hip_runtime.h>

// Problem constants (B,C,D,H,W) = (2,4,96,160,160)
#define NB 2
#define NC 4
#define ND 96
#define NH 160
#define NW 160

// Math (verified exact rounds 1-6): sy == sz (identical 2D 3x3 kernels),
// depth padding adds only zero slices, sobel(p)-sobel(t) = sobel(q) with
// q = softmax(pred) - onehot(target):
//   loss = sum(gx^2 + 2*gy^2) * SCALE
// separable: d = q[x+1]-q[x-1], s = q[x-1]+2q[x]+q[x+1],
//            gx = d[y-1]+2d[y]+d[y+1], gy = s[y+1]-s[y-1].
//
// Perf history:
//  r4/r5: __launch_bounds__(256,6) VGPR cap -> 128 MB scratch spill. Fixed.
//  r2/r3/r6 fit dur ~= #same-address-atomicAdds x 20ns exactly -> the
//  bottleneck is cross-XCD serialization on the single output address.
//  This version: per-block partial -> d_ws (plain store), tiny reduce kernel.
constexpr int TH    = 8;              // output rows per band
constexpr int SR    = TH + 2;         // staged rows (vertical halo)
constexpr int NBAND = NH / TH;        // 20 bands per slice
constexpr int PITCH = NW;             // staged row pitch in float4 cells
constexpr int NCELL = SR * PITCH;     // 1600 cells (float4 each) = 25.6 KB
constexpr int NSLOT = NCELL / 4;      // 400 4-pixel staging slots
constexpr int NPART = NBAND * NB * ND;           // 3840 partials
constexpr float SCALE = 1.0f / (2.0f * 98.0f * 162.0f * 162.0f * 4.0f);

// Rotate 16-B cells within each 64-B group so a thread's 4 consecutive
// ds_write_b128 spread banks; reads are a lane-permutation of consecutive
// cells. Measured cost: 0.77M cyc (~0.3 us) - acceptable.
__device__ __forceinline__ int cell(int i) {
    return (i & ~3) | ((i + (i >> 2)) & 3);
}

// One pixel: softmax over 4 class logits minus onehot(target).
__device__ __forceinline__ float4 qcalc(float p0, float p1, float p2, float p3,
                                        int t, bool valid) {
    float4 v = make_float4(0.f, 0.f, 0.f, 0.f);
    if (valid) {
        const float m  = fmaxf(fmaxf(p0, p1), fmaxf(p2, p3));
        const float e0 = __expf(p0 - m);
        const float e1 = __expf(p1 - m);
        const float e2 = __expf(p2 - m);
        const float e3 = __expf(p3 - m);
        const float inv = 1.0f / (e0 + e1 + e2 + e3);
        v.x = e0 * inv - (t == 0 ? 1.f : 0.f);
        v.y = e1 * inv - (t == 1 ? 1.f : 0.f);
        v.z = e2 * inv - (t == 2 ? 1.f : 0.f);
        v.w = e3 * inv - (t == 3 ? 1.f : 0.f);
    }
    return v;
}

__global__ __launch_bounds__(256) void boundary_loss_kernel(
    const float* __restrict__ pred,   // (B,C,D,H,W) f32
    const int*   __restrict__ target, // (B,D,H,W) i32
    float* __restrict__ part)         // NPART per-block partials
{
    __shared__ float4 q4s[NCELL];     // 25.6 KB, swizzled class-interleaved
    __shared__ float wsum[4];

    const int tid   = threadIdx.x;
    const int slice = blockIdx.y;     // b*ND + d
    const int b     = slice / ND;
    const int d     = slice - b * ND;
    const int y0    = blockIdx.x * TH;

    const size_t cs4   = (size_t)ND * NH * NW / 4;   // class stride in float4
    const size_t pbase = ((size_t)b * NC * ND + d) * (size_t)(NH * NW);
    const size_t tbase = ((size_t)b * ND + d) * (size_t)(NH * NW);

    // ---- Load phase: slot A = tid, slot B = tid + 256 (tid < 144) ----
    const int  rA   = tid / 40;
    const int  cA   = tid - rA * 40;
    const int  gyA  = y0 - 1 + rA;
    const bool vA   = (gyA >= 0) && (gyA < NH);
    const int  gyAc = min(max(gyA, 0), NH - 1);

    const int  sB   = tid + 256;
    const bool hasB = (sB < NSLOT);
    const int  rB   = sB / 40;
    const int  cB   = sB - rB * 40;
    const int  gyB  = y0 - 1 + rB;
    const bool vB   = hasB && (gyB >= 0) && (gyB < NH);
    const int  gyBc = min(max(gyB, 0), NH - 1);

    // All loads into named registers, issued back-to-back (one latency
    // exposure); default VGPR budget keeps them resident (no scratch).
    const float4* ppA = (const float4*)(pred + pbase + (size_t)gyAc * NW) + cA;
    const float4 a0 = ppA[0];
    const float4 a1 = ppA[cs4];
    const float4 a2 = ppA[2 * cs4];
    const float4 a3 = ppA[3 * cs4];
    const int4   ta = ((const int4*)(target + tbase + (size_t)gyAc * NW))[cA];

    const int cBs  = hasB ? cB : 0;   // safe address for inactive threads
    const int gyBs = hasB ? gyBc : 0;
    const float4* ppB = (const float4*)(pred + pbase + (size_t)gyBs * NW) + cBs;
    const float4 b0 = ppB[0];
    const float4 b1 = ppB[cs4];
    const float4 b2 = ppB[2 * cs4];
    const float4 b3 = ppB[3 * cs4];
    const int4   tb = ((const int4*)(target + tbase + (size_t)gyBs * NW))[cBs];

    // ---- Softmax + stage into LDS (explicit components, no arrays) ----
    {
        const int fA = rA * PITCH + 4 * cA;
        q4s[cell(fA + 0)] = qcalc(a0.x, a1.x, a2.x, a3.x, ta.x, vA);
        q4s[cell(fA + 1)] = qcalc(a0.y, a1.y, a2.y, a3.y, ta.y, vA);
        q4s[cell(fA + 2)] = qcalc(a0.z, a1.z, a2.z, a3.z, ta.z, vA);
        q4s[cell(fA + 3)] = qcalc(a0.w, a1.w, a2.w, a3.w, ta.w, vA);
    }
    if (hasB) {
        const int fB = rB * PITCH + 4 * cB;
        q4s[cell(fB + 0)] = qcalc(b0.x, b1.x, b2.x, b3.x, tb.x, vB);
        q4s[cell(fB + 1)] = qcalc(b0.y, b1.y, b2.y, b3.y, tb.y, vB);
        q4s[cell(fB + 2)] = qcalc(b0.z, b1.z, b2.z, b3.z, tb.z, vB);
        q4s[cell(fB + 3)] = qcalc(b0.w, b1.w, b2.w, b3.w, tb.w, vB);
    }
    __syncthreads();

    // ---- Vertical rolling Sobel: thread t owns column x = t (t < 160) ----
    float acc = 0.f;
    if (tid < NW) {
        float smm0 = 0.f, sm0 = 0.f, dmm0 = 0.f, dm0 = 0.f;
        float smm1 = 0.f, sm1 = 0.f, dmm1 = 0.f, dm1 = 0.f;
        float smm2 = 0.f, sm2 = 0.f, dmm2 = 0.f, dm2 = 0.f;
        float smm3 = 0.f, sm3 = 0.f, dmm3 = 0.f, dm3 = 0.f;

#define CLS(L, M, R, smm, sm, dmm, dm)                                    \
        do {                                                              \
            const float sn = (L) + 2.f * (M) + (R);                       \
            const float dn = (R) - (L);                                   \
            if (t >= 2) {                                                 \
                const float gx = (dmm) + 2.f * (dm) + dn;                 \
                const float gy = sn - (smm);                              \
                acc += gx * gx + 2.f * gy * gy;                           \
            }                                                             \
            smm = sm; sm = sn; dmm = dm; dm = dn;                         \
        } while (0)

        #pragma unroll
        for (int t = 0; t < SR; ++t) {
            const int base = t * PITCH + tid;
            const float4 qm = q4s[cell(base)];
            float4 ql = make_float4(0.f, 0.f, 0.f, 0.f);
            float4 qr = make_float4(0.f, 0.f, 0.f, 0.f);
            if (tid > 0)      ql = q4s[cell(base - 1)];
            if (tid < NW - 1) qr = q4s[cell(base + 1)];
            CLS(ql.x, qm.x, qr.x, smm0, sm0, dmm0, dm0);
            CLS(ql.y, qm.y, qr.y, smm1, sm1, dmm1, dm1);
            CLS(ql.z, qm.z, qr.z, smm2, sm2, dmm2, dm2);
            CLS(ql.w, qm.w, qr.w, smm3, sm3, dmm3, dm3);
        }
#undef CLS
    }

    // ---- Block reduction -> ONE PLAIN STORE per block (no atomics) ----
    #pragma unroll
    for (int off = 32; off > 0; off >>= 1)
        acc += __shfl_down(acc, off, 64);
    if ((tid & 63) == 0) wsum[tid >> 6] = acc;
    __syncthreads();
    if (tid == 0) {
        part[blockIdx.y * NBAND + blockIdx.x] =
            wsum[0] + wsum[1] + wsum[2] + wsum[3];
    }
}

__global__ __launch_bounds__(256) void reduce_partials_kernel(
    const float* __restrict__ part, float* __restrict__ out)
{
    const int tid = threadIdx.x;
    float s = 0.f;
    #pragma unroll
    for (int i = 0; i < NPART / 256; ++i)     // 15 loads, coalesced
        s += part[tid + i * 256];
    #pragma unroll
    for (int off = 32; off > 0; off >>= 1)
        s += __shfl_down(s, off, 64);
    __shared__ float wsum[4];
    if ((tid & 63) == 0) wsum[tid >> 6] = s;
    __syncthreads();
    if (tid == 0)
        out[0] = (wsum[0] + wsum[1] + wsum[2] + wsum[3]) * SCALE;
}

extern "C" void kernel_launch(void* const* d_in, const int* in_sizes, int n_in,
                              void* d_out, int out_size, void* d_ws, size_t ws_size,
                              hipStream_t stream) {
    const float* pred   = (const float*)d_in[0];
    const int*   target = (const int*)d_in[1];
    float*       out    = (float*)d_out;
    float*       part   = (float*)d_ws;      // NPART*4 = 15 KB of scratch

    dim3 grid(NBAND, NB * ND);   // 20 x 192 = 3840 blocks
    boundary_loss_kernel<<<grid, 256, 0, stream>>>(pred, target, part);
    reduce_partials_kernel<<<1, 256, 0, stream>>>(part, out);
}

// Round 8
// 128.135 us; speedup vs baseline: 1.4886x; 1.0291x over previous
//
#include <hip/hip_runtime.h>
#include <hip/hip_fp16.h>

// Problem constants (B,C,D,H,W) = (2,4,96,160,160)
#define NB 2
#define NC 4
#define ND 96
#define NH 160
#define NW 160

// Math (verified exact rounds 1-7): sy == sz (identical 2D 3x3 kernels),
// depth padding adds only zero slices, sobel(p)-sobel(t) = sobel(q) with
// q = softmax(pred) - onehot(target):
//   loss = sum(gx^2 + 2*gy^2) * SCALE
// separable: d = q[x+1]-q[x-1], s = q[x-1]+2q[x]+q[x+1],
//            gx = d[y-1]+2d[y]+d[y+1], gy = s[y+1]-s[y-1].
//
// Perf history:
//  r4/r5: __launch_bounds__(256,6) VGPR cap -> 128 MB scratch spill. Fixed:
//         never add an occupancy floor here.
//  r2..r6: dur == #same-address-atomicAdds x ~20ns -> single-address atomics
//         serialize cross-XCD. Fixed in r7: plain per-block partial stores to
//         d_ws + tiny reduce kernel (kernel 75 -> ~49 us).
//  r8 (this): fp16-packed LDS class-pair planes: no swizzle, conflict-free
//         b128 staging writes + b32 reads, packed-half Sobel math, 13 KB LDS
//         -> 8 blocks/CU.
constexpr int TH    = 8;              // output rows per band
constexpr int SR    = TH + 2;         // staged rows (vertical halo)
constexpr int NBAND = NH / TH;        // 20 bands per slice
constexpr int NSLOT = SR * NW / 4;    // 400 4-pixel staging slots
constexpr int PCELL = SR * NW;        // 1600 px cells per plane
constexpr int ZCELL = PCELL;          // always-zero guard cell (x-boundary)
constexpr int NPART = NBAND * NB * ND;           // 3840 partials
constexpr float SCALE = 1.0f / (2.0f * 98.0f * 162.0f * 162.0f * 4.0f);

__device__ __forceinline__ __half2 ld_h2(const unsigned int* p, int i) {
    return __builtin_bit_cast(__half2, p[i]);
}

// One pixel: softmax over 4 class logits minus onehot(target), packed as
// two half2 (classes 01 -> a, classes 23 -> b).
__device__ __forceinline__ void qcalc(float p0, float p1, float p2, float p3,
                                      int t, bool valid,
                                      unsigned int& ha, unsigned int& hb) {
    float q0 = 0.f, q1 = 0.f, q2 = 0.f, q3 = 0.f;
    if (valid) {
        const float m  = fmaxf(fmaxf(p0, p1), fmaxf(p2, p3));
        const float e0 = __expf(p0 - m);
        const float e1 = __expf(p1 - m);
        const float e2 = __expf(p2 - m);
        const float e3 = __expf(p3 - m);
        const float inv = 1.0f / (e0 + e1 + e2 + e3);
        q0 = e0 * inv - (t == 0 ? 1.f : 0.f);
        q1 = e1 * inv - (t == 1 ? 1.f : 0.f);
        q2 = e2 * inv - (t == 2 ? 1.f : 0.f);
        q3 = e3 * inv - (t == 3 ? 1.f : 0.f);
    }
    ha = __builtin_bit_cast(unsigned int, __floats2half2_rn(q0, q1));
    hb = __builtin_bit_cast(unsigned int, __floats2half2_rn(q2, q3));
}

__global__ __launch_bounds__(256) void boundary_loss_kernel(
    const float* __restrict__ pred,   // (B,C,D,H,W) f32
    const int*   __restrict__ target, // (B,D,H,W) i32
    float* __restrict__ part)         // NPART per-block partials
{
    __shared__ unsigned int pa[PCELL + 4];  // classes 0,1 packed half2
    __shared__ unsigned int pb[PCELL + 4];  // classes 2,3 packed half2
    __shared__ float wsum[4];

    const int tid   = threadIdx.x;
    const int slice = blockIdx.y;     // b*ND + d
    const int b     = slice / ND;
    const int d     = slice - b * ND;
    const int y0    = blockIdx.x * TH;

    const size_t cs4   = (size_t)ND * NH * NW / 4;   // class stride in float4
    const size_t pbase = ((size_t)b * NC * ND + d) * (size_t)(NH * NW);
    const size_t tbase = ((size_t)b * ND + d) * (size_t)(NH * NW);

    // ---- Load phase: slot A = tid, slot B = tid + 256 (tid < 144) ----
    const int  rA   = tid / 40;
    const int  cA   = tid - rA * 40;
    const int  gyA  = y0 - 1 + rA;
    const bool vA   = (gyA >= 0) && (gyA < NH);
    const int  gyAc = min(max(gyA, 0), NH - 1);

    const int  sB   = tid + 256;
    const bool hasB = (sB < NSLOT);
    const int  rB   = sB / 40;
    const int  cB   = sB - rB * 40;
    const int  gyB  = y0 - 1 + rB;
    const bool vB   = hasB && (gyB >= 0) && (gyB < NH);
    const int  gyBc = min(max(gyB, 0), NH - 1);

    // All loads into named registers, issued back-to-back (one latency
    // exposure); default VGPR budget keeps them resident (no scratch).
    const float4* ppA = (const float4*)(pred + pbase + (size_t)gyAc * NW) + cA;
    const float4 a0 = ppA[0];
    const float4 a1 = ppA[cs4];
    const float4 a2 = ppA[2 * cs4];
    const float4 a3 = ppA[3 * cs4];
    const int4   ta = ((const int4*)(target + tbase + (size_t)gyAc * NW))[cA];

    const int cBs  = hasB ? cB : 0;   // safe address for inactive threads
    const int gyBs = hasB ? gyBc : 0;
    const float4* ppB = (const float4*)(pred + pbase + (size_t)gyBs * NW) + cBs;
    const float4 b0 = ppB[0];
    const float4 b1 = ppB[cs4];
    const float4 b2 = ppB[2 * cs4];
    const float4 b3 = ppB[3 * cs4];
    const int4   tb = ((const int4*)(target + tbase + (size_t)gyBs * NW))[cBs];

    // ---- Softmax + pack + stage: one b128 per plane per slot ----
    {
        uint4 wa, wb;
        qcalc(a0.x, a1.x, a2.x, a3.x, ta.x, vA, wa.x, wb.x);
        qcalc(a0.y, a1.y, a2.y, a3.y, ta.y, vA, wa.y, wb.y);
        qcalc(a0.z, a1.z, a2.z, a3.z, ta.z, vA, wa.z, wb.z);
        qcalc(a0.w, a1.w, a2.w, a3.w, ta.w, vA, wa.w, wb.w);
        ((uint4*)pa)[rA * 40 + cA] = wa;   // 16-B lane stride: conflict-free
        ((uint4*)pb)[rA * 40 + cA] = wb;
    }
    if (hasB) {
        uint4 wa, wb;
        qcalc(b0.x, b1.x, b2.x, b3.x, tb.x, vB, wa.x, wb.x);
        qcalc(b0.y, b1.y, b2.y, b3.y, tb.y, vB, wa.y, wb.y);
        qcalc(b0.z, b1.z, b2.z, b3.z, tb.z, vB, wa.z, wb.z);
        qcalc(b0.w, b1.w, b2.w, b3.w, tb.w, vB, wa.w, wb.w);
        ((uint4*)pa)[rB * 40 + cB] = wa;
        ((uint4*)pb)[rB * 40 + cB] = wb;
    }
    if (tid == 0) { pa[ZCELL] = 0u; pb[ZCELL] = 0u; }  // x-boundary guard
    __syncthreads();

    // ---- Vertical rolling Sobel (packed half2): column x = tid < 160 ----
    float acc = 0.f;
    if (tid < NW) {
        // branchless rolling addresses; boundary lanes pin l/r to ZCELL
        int am = tid;
        int al = (tid > 0)      ? tid - 1 : ZCELL;
        int ar = (tid < NW - 1) ? tid + 1 : ZCELL;
        const int il = (tid > 0)      ? NW : 0;
        const int ir = (tid < NW - 1) ? NW : 0;

        const __half2 two = __floats2half2_rn(2.f, 2.f);
        const __half2 hz  = __floats2half2_rn(0.f, 0.f);
        __half2 smmA = hz, smA = hz, dmmA = hz, dmA = hz;
        __half2 smmB = hz, smB = hz, dmmB = hz, dmB = hz;

#define CLS(P, smm, sm, dmm, dm)                                          \
        do {                                                              \
            const __half2 l = ld_h2(P, al);                               \
            const __half2 m = ld_h2(P, am);                               \
            const __half2 r = ld_h2(P, ar);                               \
            const __half2 sn = __hadd2(__hfma2(m, two, l), r);            \
            const __half2 dn = __hsub2(r, l);                             \
            if (t >= 2) {                                                 \
                const __half2 gx = __hadd2(__hfma2(dm, two, dmm), dn);    \
                const __half2 gy = __hsub2(sn, smm);                      \
                const __half2 rs = __hfma2(__hmul2(gy, gy), two,          \
                                           __hmul2(gx, gx));              \
                acc += __low2float(rs) + __high2float(rs);                \
            }                                                             \
            smm = sm; sm = sn; dmm = dm; dm = dn;                         \
        } while (0)

        #pragma unroll
        for (int t = 0; t < SR; ++t) {
            CLS(pa, smmA, smA, dmmA, dmA);
            CLS(pb, smmB, smB, dmmB, dmB);
            am += NW; al += il; ar += ir;
        }
#undef CLS
    }

    // ---- Block reduction -> ONE PLAIN STORE per block (no atomics) ----
    #pragma unroll
    for (int off = 32; off > 0; off >>= 1)
        acc += __shfl_down(acc, off, 64);
    if ((tid & 63) == 0) wsum[tid >> 6] = acc;
    __syncthreads();
    if (tid == 0) {
        part[blockIdx.y * NBAND + blockIdx.x] =
            wsum[0] + wsum[1] + wsum[2] + wsum[3];
    }
}

__global__ __launch_bounds__(256) void reduce_partials_kernel(
    const float* __restrict__ part, float* __restrict__ out)
{
    const int tid = threadIdx.x;
    float s = 0.f;
    #pragma unroll
    for (int i = 0; i < NPART / 256; ++i)     // 15 loads, coalesced
        s += part[tid + i * 256];
    #pragma unroll
    for (int off = 32; off > 0; off >>= 1)
        s += __shfl_down(s, off, 64);
    __shared__ float wsum[4];
    if ((tid & 63) == 0) wsum[tid >> 6] = s;
    __syncthreads();
    if (tid == 0)
        out[0] = (wsum[0] + wsum[1] + wsum[2] + wsum[3]) * SCALE;
}

extern "C" void kernel_launch(void* const* d_in, const int* in_sizes, int n_in,
                              void* d_out, int out_size, void* d_ws, size_t ws_size,
                              hipStream_t stream) {
    const float* pred   = (const float*)d_in[0];
    const int*   target = (const int*)d_in[1];
    float*       out    = (float*)d_out;
    float*       part   = (float*)d_ws;      // NPART*4 = 15 KB of scratch

    dim3 grid(NBAND, NB * ND);   // 20 x 192 = 3840 blocks
    boundary_loss_kernel<<<grid, 256, 0, stream>>>(pred, target, part);
    reduce_partials_kernel<<<1, 256, 0, stream>>>(part, out);
}